// Round 1
// baseline (238.467 us; speedup 1.0000x reference)
//
#include <hip/hip_runtime.h>

typedef unsigned short ushort_t;
typedef __bf16 bf16x8 __attribute__((ext_vector_type(8)));
typedef float f32x4 __attribute__((ext_vector_type(4)));

#define T_SOFT 32.0f
#define THRESH 0.76604444311897803f   // cos(40 deg)

__device__ __forceinline__ ushort_t f2bf(float f) {
  union { float f; unsigned u; } x; x.f = f;
  unsigned r = (x.u + 0x7fffu + ((x.u >> 16) & 1u)) >> 16;  // RNE
  return (ushort_t)r;
}

// ---------------- conversions ----------------
__global__ void cvt_bf16_k(const float* __restrict__ src, ushort_t* __restrict__ dst, int n) {
  int i = blockIdx.x * blockDim.x + threadIdx.x;
  if (i < n) dst[i] = f2bf(src[i]);
}

// src [R,C] fp32 -> dst [C, Rpad] bf16 (transposed, K-padded with zeros)
__global__ void cvt_tr_k(const float* __restrict__ src, ushort_t* __restrict__ dst,
                         int R, int C, int Rpad) {
  int i = blockIdx.x * blockDim.x + threadIdx.x;
  if (i >= C * Rpad) return;
  int c = i / Rpad;
  int r = i - c * Rpad;
  dst[i] = (r < R) ? f2bf(src[r * C + c]) : (ushort_t)0;
}

// ---------------- gn = normalize(attributes @ att_g) ----------------
// block: 128 threads, 8 rows of C per block, 125 blocks
__global__ __launch_bounds__(128) void gn_k(const float* __restrict__ attributes,
                                            const float* __restrict__ att_g,
                                            float* __restrict__ gn) {
  __shared__ float a_lds[8][312];
  __shared__ float red2[8][2];
  int h = threadIdx.x;
  int c0 = blockIdx.x * 8;
  for (int idx = h; idx < 8 * 312; idx += 128) {
    int r = idx / 312;
    int k = idx - r * 312;
    a_lds[r][k] = attributes[(c0 + r) * 312 + k];
  }
  __syncthreads();
  float acc[8] = {0.f,0.f,0.f,0.f,0.f,0.f,0.f,0.f};
  for (int k = 0; k < 312; ++k) {
    float w = att_g[k * 128 + h];   // coalesced across h
    #pragma unroll
    for (int r = 0; r < 8; ++r) acc[r] += a_lds[r][k] * w;
  }
  int lane = h & 63, wvid = h >> 6;
  #pragma unroll
  for (int r = 0; r < 8; ++r) {
    float v = acc[r] * acc[r];
    #pragma unroll
    for (int off = 32; off > 0; off >>= 1) v += __shfl_xor(v, off, 64);
    if (lane == 0) red2[r][wvid] = v;
  }
  __syncthreads();
  #pragma unroll
  for (int r = 0; r < 8; ++r) {
    float nrm = fmaxf(sqrtf(red2[r][0] + red2[r][1]), 1e-12f);
    gn[(c0 + r) * 128 + h] = acc[r] / nrm;
  }
}

// ---------------- MFMA GEMM: C[M,N] = A[M,K](bf16) @ BT[N,K](bf16)^T (+bias[col]) ----------------
// one wave per 16x16 C tile; A/BT padded to 16-multiples of rows; K multiple of 32
__global__ __launch_bounds__(256) void mfma_gemm_bt(
    const ushort_t* __restrict__ A, const ushort_t* __restrict__ BT,
    float* __restrict__ C, int M, int N, int K, int Mt, int Nt,
    const float* __restrict__ bias) {
  int wid = blockIdx.x * 4 + (threadIdx.x >> 6);
  int lane = threadIdx.x & 63;
  int tm = wid / Nt;
  int tn = wid - tm * Nt;
  if (tm >= Mt) return;
  int l15 = lane & 15;
  int quad = lane >> 4;
  const bf16x8* ap = reinterpret_cast<const bf16x8*>(A + (size_t)(tm * 16 + l15) * K + quad * 8);
  const bf16x8* bp = reinterpret_cast<const bf16x8*>(BT + (size_t)(tn * 16 + l15) * K + quad * 8);
  f32x4 acc = {0.f, 0.f, 0.f, 0.f};
  int steps = K >> 5;
  for (int s = 0; s < steps; ++s) {
    bf16x8 a = ap[s * 4];       // 32 bf16 stride per step
    bf16x8 b = bp[s * 4];
    acc = __builtin_amdgcn_mfma_f32_16x16x32_bf16(a, b, acc, 0, 0, 0);
  }
  int col = tn * 16 + l15;
  if (col >= N) return;
  float bv = bias ? bias[col] : 0.f;
  int row0 = tm * 16 + quad * 4;   // C/D: col=lane&15, row=(lane>>4)*4+reg
  #pragma unroll
  for (int r = 0; r < 4; ++r) {
    int row = row0 + r;
    if (row < M) C[(size_t)row * N + col] = acc[r] + bv;
  }
}

// ---------------- fused sim -> mask -> softmax -> propagate ----------------
// block: 320 threads, 4 rows i per block, 250 blocks
__global__ __launch_bounds__(320) void attn_prop_k(
    const float* __restrict__ gn, const float* __restrict__ attributes,
    const float* __restrict__ proto_red, ushort_t* __restrict__ outs) {
  __shared__ float gni[4][128];
  __shared__ float wv[4][1000];
  __shared__ float wred[4];
  __shared__ int njs;
  __shared__ int jlist[1000];
  int tid = threadIdx.x;
  int i0 = blockIdx.x * 4;
  if (tid < 4) wred[tid] = 0.f;
  if (tid == 0) njs = 0;
  for (int idx = tid; idx < 512; idx += 320) gni[idx >> 7][idx & 127] = gn[i0 * 128 + idx];
  __syncthreads();
  float lsum[4] = {0.f,0.f,0.f,0.f};
  for (int j = tid; j < 1000; j += 320) {
    const float4* gj = reinterpret_cast<const float4*>(gn + (size_t)j * 128);
    float d[4] = {0.f,0.f,0.f,0.f};
    #pragma unroll 4
    for (int k4 = 0; k4 < 32; ++k4) {
      float4 v = gj[k4];
      int k = k4 * 4;
      #pragma unroll
      for (int r = 0; r < 4; ++r)
        d[r] += v.x * gni[r][k] + v.y * gni[r][k+1] + v.z * gni[r][k+2] + v.w * gni[r][k+3];
    }
    int any = 0;
    #pragma unroll
    for (int r = 0; r < 4; ++r) {
      float w = (d[r] > THRESH) ? __expf(T_SOFT * d[r]) : 0.f;  // exp(T*sim); max-shift cancels in normalize
      wv[r][j] = w;
      lsum[r] += w;
      any |= (w > 0.f) ? 1 : 0;
    }
    if (any) { int p = atomicAdd(&njs, 1); jlist[p] = j; }
  }
  #pragma unroll
  for (int r = 0; r < 4; ++r) {
    float v = lsum[r];
    #pragma unroll
    for (int off = 32; off > 0; off >>= 1) v += __shfl_down(v, off, 64);
    if ((tid & 63) == 0) atomicAdd(&wred[r], v);
  }
  __syncthreads();
  if (tid < 312) {
    int nj = njs;
    float aa[4] = {0.f,0.f,0.f,0.f}, pp[4] = {0.f,0.f,0.f,0.f};
    for (int t = 0; t < nj; ++t) {
      int j = jlist[t];
      float av = attributes[(size_t)j * 312 + tid];
      float pv = proto_red[(size_t)j * 312 + tid];
      #pragma unroll
      for (int r = 0; r < 4; ++r) {
        float w = wv[r][j];
        aa[r] += w * av;
        pp[r] += w * pv;
      }
    }
    #pragma unroll
    for (int r = 0; r < 4; ++r) {
      float inv = 1.f / wred[r];
      size_t rowoff = (size_t)(i0 + r) * 640;
      outs[rowoff + tid]       = f2bf(aa[r] * inv);   // att_outs -> cols [0,312)
      outs[rowoff + 312 + tid] = f2bf(pp[r] * inv);   // img_proto_outs -> cols [312,624)
    }
  }
  if (tid < 16) {
    #pragma unroll
    for (int r = 0; r < 4; ++r) outs[(size_t)(i0 + r) * 640 + 624 + tid] = 0;  // K-pad zeros
  }
}

// ---------------- final: out[b,c] = fc_b + sum_h relu(img_h[b,h]+ph[c,h]) * fc_w[h] ----------------
// 64x64 tile per block, 4x4 per thread
__global__ __launch_bounds__(256) void final_k(
    const float* __restrict__ img_h, const float* __restrict__ ph,
    const float* __restrict__ fc_w, const float* __restrict__ fc_b,
    float* __restrict__ out) {
  __shared__ float ih[64][129];   // +1 pad: 16 tx rows stride 516 -> 2-way bank alias (free)
  __shared__ float ps[64][129];
  __shared__ float ws_[128];
  int tid = threadIdx.x;
  int b0 = blockIdx.x * 64;
  int c0 = blockIdx.y * 64;
  for (int idx = tid; idx < 2048; idx += 256) {
    int row = idx >> 5, c4 = (idx & 31) * 4;
    float4 v = *reinterpret_cast<const float4*>(img_h + (size_t)(b0 + row) * 128 + c4);
    ih[row][c4] = v.x; ih[row][c4+1] = v.y; ih[row][c4+2] = v.z; ih[row][c4+3] = v.w;
  }
  for (int idx = tid; idx < 2048; idx += 256) {
    int row = idx >> 5, c4 = (idx & 31) * 4;
    int c = c0 + row;
    float4 v = make_float4(0.f, 0.f, 0.f, 0.f);
    if (c < 1000) v = *reinterpret_cast<const float4*>(ph + (size_t)c * 128 + c4);
    ps[row][c4] = v.x; ps[row][c4+1] = v.y; ps[row][c4+2] = v.z; ps[row][c4+3] = v.w;
  }
  if (tid < 128) ws_[tid] = fc_w[tid];
  __syncthreads();
  int tx = tid & 15, ty = tid >> 4;
  float acc[4][4] = {};
  #pragma unroll 2
  for (int h = 0; h < 128; ++h) {
    float w = ws_[h];
    float a[4], p[4];
    #pragma unroll
    for (int i = 0; i < 4; ++i) a[i] = ih[ty * 4 + i][h];
    #pragma unroll
    for (int j = 0; j < 4; ++j) p[j] = ps[tx * 4 + j][h];
    #pragma unroll
    for (int i = 0; i < 4; ++i)
      #pragma unroll
      for (int j = 0; j < 4; ++j)
        acc[i][j] += fmaxf(a[i] + p[j], 0.f) * w;
  }
  float fb = fc_b[0];
  #pragma unroll
  for (int i = 0; i < 4; ++i) {
    int b = b0 + ty * 4 + i;
    int c = c0 + tx * 4;
    if (c < 1000) {   // 1000 % 4 == 0 -> all-or-nothing per float4
      float4 v = make_float4(acc[i][0] + fb, acc[i][1] + fb, acc[i][2] + fb, acc[i][3] + fb);
      *reinterpret_cast<float4*>(out + (size_t)b * 1000 + c) = v;
    }
  }
}

extern "C" void kernel_launch(void* const* d_in, const int* in_sizes, int n_in,
                              void* d_out, int out_size, void* d_ws, size_t ws_size,
                              hipStream_t stream) {
  const float* image_feats = (const float*)d_in[0];   // [2048,2048]
  const float* img_proto   = (const float*)d_in[1];   // [1000,2048]
  const float* attributes  = (const float*)d_in[2];   // [1000,312]
  const float* att_g   = (const float*)d_in[4];       // [312,128]
  const float* slim_w  = (const float*)d_in[5];       // [2048,312]
  const float* slim_b  = (const float*)d_in[6];       // [312]
  const float* img_w   = (const float*)d_in[7];       // [2048,128]
  const float* proto_w = (const float*)d_in[8];       // [624,128]
  const float* proto_b = (const float*)d_in[9];       // [1,128]
  const float* fc_w    = (const float*)d_in[10];      // [128,1]
  const float* fc_b    = (const float*)d_in[11];      // [1]
  float* out = (float*)d_out;                         // [2048,1000]

  char* ws = (char*)d_ws;
  size_t o = 0;
  auto alloc = [&](size_t bytes) { size_t r = o; o += (bytes + 255) & ~(size_t)255; return r; };
  ushort_t* imgf_bf = (ushort_t*)(ws + alloc(2048ull * 2048 * 2));  // image_feats bf16 [2048,2048]
  ushort_t* imgwT   = (ushort_t*)(ws + alloc(128ull * 2048 * 2));   // img_w^T bf16 [128,2048]
  ushort_t* imgp_bf = (ushort_t*)(ws + alloc(1008ull * 2048 * 2));  // img_proto bf16, M-pad 1008
  ushort_t* slimT   = (ushort_t*)(ws + alloc(320ull * 2048 * 2));   // slim_w^T bf16, N-pad 320
  ushort_t* protowT = (ushort_t*)(ws + alloc(128ull * 640 * 2));    // proto_w^T bf16, K-pad 640 (zeroed)
  float* gn        = (float*)(ws + alloc(1000ull * 128 * 4));
  float* proto_red = (float*)(ws + alloc(1000ull * 312 * 4));
  ushort_t* outs_bf = (ushort_t*)(ws + alloc(1008ull * 640 * 2));   // concat outs bf16, M-pad/K-pad
  float* img_h     = (float*)(ws + alloc(2048ull * 128 * 4));
  float* ph        = (float*)(ws + alloc(1000ull * 128 * 4));       // proto_h + proto_b

  cvt_bf16_k<<<(2048 * 2048 + 255) / 256, 256, 0, stream>>>(image_feats, imgf_bf, 2048 * 2048);
  cvt_bf16_k<<<(1000 * 2048 + 255) / 256, 256, 0, stream>>>(img_proto, imgp_bf, 1000 * 2048);
  cvt_tr_k<<<(312 * 2048 + 255) / 256, 256, 0, stream>>>(slim_w, slimT, 2048, 312, 2048);
  cvt_tr_k<<<(128 * 2048 + 255) / 256, 256, 0, stream>>>(img_w, imgwT, 2048, 128, 2048);
  cvt_tr_k<<<(128 * 640 + 255) / 256, 256, 0, stream>>>(proto_w, protowT, 624, 128, 640);

  gn_k<<<125, 128, 0, stream>>>(attributes, att_g, gn);

  // proto_red = img_proto @ slim_w + slim_b   (M=1000,N=312,K=2048)
  mfma_gemm_bt<<<(63 * 20 + 3) / 4, 256, 0, stream>>>(imgp_bf, slimT, proto_red,
                                                      1000, 312, 2048, 63, 20, slim_b);
  // img_h = image_feats @ img_w               (M=2048,N=128,K=2048)
  mfma_gemm_bt<<<(128 * 8 + 3) / 4, 256, 0, stream>>>(imgf_bf, imgwT, img_h,
                                                      2048, 128, 2048, 128, 8, nullptr);

  attn_prop_k<<<250, 320, 0, stream>>>(gn, attributes, proto_red, outs_bf);

  // ph = outs @ proto_w + proto_b             (M=1000,N=128,K=640 padded)
  mfma_gemm_bt<<<(63 * 8 + 3) / 4, 256, 0, stream>>>(outs_bf, protowT, ph,
                                                     1000, 128, 640, 63, 8, proto_b);

  final_k<<<dim3(32, 16), 256, 0, stream>>>(img_h, ph, fc_w, fc_b, out);
}

// Round 2
// 226.887 us; speedup vs baseline: 1.0510x; 1.0510x over previous
//
#include <hip/hip_runtime.h>

typedef unsigned short ushort_t;
typedef __bf16 bf16x8 __attribute__((ext_vector_type(8)));
typedef float f32x4 __attribute__((ext_vector_type(4)));
typedef ushort_t us8 __attribute__((ext_vector_type(8)));

#define T_SOFT 32.0f
#define THRESH 0.76604444311897803f   // cos(40 deg)

__device__ __forceinline__ ushort_t f2bf(float f) {
  union { float f; unsigned u; } x; x.f = f;
  unsigned r = (x.u + 0x7fffu + ((x.u >> 16) & 1u)) >> 16;  // RNE
  return (ushort_t)r;
}

// ---------------- merged straight conversions (fp32 -> bf16), 8 elem/thread ----------------
// region0: nb0 blocks over s0/d0; region1: rest over s1/d1. Sizes exact multiples of 2048.
__global__ __launch_bounds__(256) void cvt2_k(const float* __restrict__ s0, ushort_t* __restrict__ d0, int nb0,
                                              const float* __restrict__ s1, ushort_t* __restrict__ d1) {
  int b = blockIdx.x;
  const float* src; ushort_t* dst; int base;
  if (b < nb0) { src = s0; dst = d0; base = b * 2048; }
  else         { src = s1; dst = d1; base = (b - nb0) * 2048; }
  int i = base + threadIdx.x * 8;
  float4 v0 = *reinterpret_cast<const float4*>(src + i);
  float4 v1 = *reinterpret_cast<const float4*>(src + i + 4);
  us8 o;
  o[0] = f2bf(v0.x); o[1] = f2bf(v0.y); o[2] = f2bf(v0.z); o[3] = f2bf(v0.w);
  o[4] = f2bf(v1.x); o[5] = f2bf(v1.y); o[6] = f2bf(v1.z); o[7] = f2bf(v1.w);
  *reinterpret_cast<us8*>(dst + i) = o;
}

// ---------------- merged transposes: src [R,C] fp32 -> dst [C, Rpad] bf16 (zero K-pad) ----------------
__global__ __launch_bounds__(256) void cvt_tr3_k(const float* __restrict__ s0, ushort_t* __restrict__ d0,
                                                 const float* __restrict__ s1, ushort_t* __restrict__ d1,
                                                 const float* __restrict__ s2, ushort_t* __restrict__ d2) {
  int b = blockIdx.x;
  const float* src; ushort_t* dst; int R, C, Rpad, i;
  if (b < 2496)      { src = s0; dst = d0; R = 2048; C = 312; Rpad = 2048; i = b * 256 + threadIdx.x; }
  else if (b < 3520) { src = s1; dst = d1; R = 2048; C = 128; Rpad = 2048; i = (b - 2496) * 256 + threadIdx.x; }
  else               { src = s2; dst = d2; R = 624;  C = 128; Rpad = 640;  i = (b - 3520) * 256 + threadIdx.x; }
  int c = i / Rpad;
  int r = i - c * Rpad;
  dst[i] = (r < R) ? f2bf(src[r * C + c]) : (ushort_t)0;
}

// ---------------- gn = normalize(attributes @ att_g) ----------------
// block: 128 threads, 8 rows of C per block, 125 blocks; k unrolled x4 for load ILP
__global__ __launch_bounds__(128) void gn_k(const float* __restrict__ attributes,
                                            const float* __restrict__ att_g,
                                            float* __restrict__ gn) {
  __shared__ float a_lds[8][316];   // stride 316: float4-aligned rows
  __shared__ float red2[8][2];
  int h = threadIdx.x;
  int c0 = blockIdx.x * 8;
  for (int idx = h; idx < 8 * 312; idx += 128) {
    int r = idx / 312;
    int k = idx - r * 312;
    a_lds[r][k] = attributes[(c0 + r) * 312 + k];
  }
  __syncthreads();
  float acc[8] = {0.f,0.f,0.f,0.f,0.f,0.f,0.f,0.f};
  for (int k = 0; k < 312; k += 4) {   // 312 % 4 == 0
    float w0 = att_g[(k + 0) * 128 + h];
    float w1 = att_g[(k + 1) * 128 + h];
    float w2 = att_g[(k + 2) * 128 + h];
    float w3 = att_g[(k + 3) * 128 + h];
    #pragma unroll
    for (int r = 0; r < 8; ++r) {
      float4 a4 = *reinterpret_cast<const float4*>(&a_lds[r][k]);
      acc[r] += a4.x * w0 + a4.y * w1 + a4.z * w2 + a4.w * w3;
    }
  }
  int lane = h & 63, wvid = h >> 6;
  #pragma unroll
  for (int r = 0; r < 8; ++r) {
    float v = acc[r] * acc[r];
    #pragma unroll
    for (int off = 32; off > 0; off >>= 1) v += __shfl_xor(v, off, 64);
    if (lane == 0) red2[r][wvid] = v;
  }
  __syncthreads();
  #pragma unroll
  for (int r = 0; r < 8; ++r) {
    float nrm = fmaxf(sqrtf(red2[r][0] + red2[r][1]), 1e-12f);
    gn[(c0 + r) * 128 + h] = acc[r] / nrm;
  }
}

// ---------------- MFMA GEMM: C[M,N] = A[M,K](bf16) @ BT[N,K](bf16)^T (+bias[col]) ----------------
// one wave per 16x16 C tile; K multiple of 128; x4 unroll with 8 loads in flight
__global__ __launch_bounds__(256) void mfma_gemm_bt(
    const ushort_t* __restrict__ A, const ushort_t* __restrict__ BT,
    float* __restrict__ C, int M, int N, int K, int Mt, int Nt,
    const float* __restrict__ bias) {
  int wid = blockIdx.x * 4 + (threadIdx.x >> 6);
  int lane = threadIdx.x & 63;
  int tm = wid / Nt;
  int tn = wid - tm * Nt;
  if (tm >= Mt) return;
  int l15 = lane & 15;
  int quad = lane >> 4;
  const bf16x8* ap = reinterpret_cast<const bf16x8*>(A + (size_t)(tm * 16 + l15) * K + quad * 8);
  const bf16x8* bp = reinterpret_cast<const bf16x8*>(BT + (size_t)(tn * 16 + l15) * K + quad * 8);
  f32x4 acc = {0.f, 0.f, 0.f, 0.f};
  for (int s = 0, steps = K >> 7; s < steps; ++s) {
    bf16x8 a0 = ap[0],  b0 = bp[0];
    bf16x8 a1 = ap[4],  b1 = bp[4];
    bf16x8 a2 = ap[8],  b2 = bp[8];
    bf16x8 a3 = ap[12], b3 = bp[12];
    ap += 16; bp += 16;
    acc = __builtin_amdgcn_mfma_f32_16x16x32_bf16(a0, b0, acc, 0, 0, 0);
    acc = __builtin_amdgcn_mfma_f32_16x16x32_bf16(a1, b1, acc, 0, 0, 0);
    acc = __builtin_amdgcn_mfma_f32_16x16x32_bf16(a2, b2, acc, 0, 0, 0);
    acc = __builtin_amdgcn_mfma_f32_16x16x32_bf16(a3, b3, acc, 0, 0, 0);
  }
  int col = tn * 16 + l15;
  if (col >= N) return;
  float bv = bias ? bias[col] : 0.f;
  int row0 = tm * 16 + quad * 4;   // C/D: col=lane&15, row=(lane>>4)*4+reg
  #pragma unroll
  for (int r = 0; r < 4; ++r) {
    int row = row0 + r;
    if (row < M) C[(size_t)row * N + col] = acc[r] + bv;
  }
}

// ---------------- fused sim -> mask -> softmax -> propagate ----------------
__global__ __launch_bounds__(320) void attn_prop_k(
    const float* __restrict__ gn, const float* __restrict__ attributes,
    const float* __restrict__ proto_red, ushort_t* __restrict__ outs) {
  __shared__ float gni[4][128];
  __shared__ float wv[4][1000];
  __shared__ float wred[4];
  __shared__ int njs;
  __shared__ int jlist[1000];
  int tid = threadIdx.x;
  int i0 = blockIdx.x * 4;
  if (tid < 4) wred[tid] = 0.f;
  if (tid == 0) njs = 0;
  for (int idx = tid; idx < 512; idx += 320) gni[idx >> 7][idx & 127] = gn[i0 * 128 + idx];
  __syncthreads();
  float lsum[4] = {0.f,0.f,0.f,0.f};
  for (int j = tid; j < 1000; j += 320) {
    const float4* gj = reinterpret_cast<const float4*>(gn + (size_t)j * 128);
    float d[4] = {0.f,0.f,0.f,0.f};
    #pragma unroll 4
    for (int k4 = 0; k4 < 32; ++k4) {
      float4 v = gj[k4];
      int k = k4 * 4;
      #pragma unroll
      for (int r = 0; r < 4; ++r)
        d[r] += v.x * gni[r][k] + v.y * gni[r][k+1] + v.z * gni[r][k+2] + v.w * gni[r][k+3];
    }
    int any = 0;
    #pragma unroll
    for (int r = 0; r < 4; ++r) {
      float w = (d[r] > THRESH) ? __expf(T_SOFT * d[r]) : 0.f;  // max-shift cancels in normalize
      wv[r][j] = w;
      lsum[r] += w;
      any |= (w > 0.f) ? 1 : 0;
    }
    if (any) { int p = atomicAdd(&njs, 1); jlist[p] = j; }
  }
  #pragma unroll
  for (int r = 0; r < 4; ++r) {
    float v = lsum[r];
    #pragma unroll
    for (int off = 32; off > 0; off >>= 1) v += __shfl_down(v, off, 64);
    if ((tid & 63) == 0) atomicAdd(&wred[r], v);
  }
  __syncthreads();
  if (tid < 312) {
    int nj = njs;
    float aa[4] = {0.f,0.f,0.f,0.f}, pp[4] = {0.f,0.f,0.f,0.f};
    for (int t = 0; t < nj; ++t) {
      int j = jlist[t];
      float av = attributes[(size_t)j * 312 + tid];
      float pv = proto_red[(size_t)j * 312 + tid];
      #pragma unroll
      for (int r = 0; r < 4; ++r) {
        float w = wv[r][j];
        aa[r] += w * av;
        pp[r] += w * pv;
      }
    }
    #pragma unroll
    for (int r = 0; r < 4; ++r) {
      float inv = 1.f / wred[r];
      size_t rowoff = (size_t)(i0 + r) * 640;
      outs[rowoff + tid]       = f2bf(aa[r] * inv);   // att_outs -> [0,312)
      outs[rowoff + 312 + tid] = f2bf(pp[r] * inv);   // img_proto_outs -> [312,624)
    }
  }
  if (tid < 16) {
    #pragma unroll
    for (int r = 0; r < 4; ++r) outs[(size_t)(i0 + r) * 640 + 624 + tid] = 0;  // K-pad
  }
}

// ---------------- final: out[b,c] = fc_b + sum_h relu(img_h[b,h]+ph[c,h]) * fc_w[h] ----------------
// 128x64 tile per block, 8x4 per thread, float4 (ds_read_b128) LDS reads
__global__ __launch_bounds__(256) void final_k(
    const float* __restrict__ img_h, const float* __restrict__ ph,
    const float* __restrict__ fc_w, const float* __restrict__ fc_b,
    float* __restrict__ out) {
  __shared__ float ih[128][132];   // 132: float4-aligned rows, breaks pow-2 strides
  __shared__ float ps[64][132];
  __shared__ float ws_[128];
  int tid = threadIdx.x;
  int b0 = blockIdx.x * 128;
  int c0 = blockIdx.y * 64;
  for (int idx = tid; idx < 4096; idx += 256) {
    int row = idx >> 5, c4 = (idx & 31) * 4;
    float4 v = *reinterpret_cast<const float4*>(img_h + (size_t)(b0 + row) * 128 + c4);
    *reinterpret_cast<float4*>(&ih[row][c4]) = v;
  }
  for (int idx = tid; idx < 2048; idx += 256) {
    int row = idx >> 5, c4 = (idx & 31) * 4;
    int c = c0 + row;
    float4 v = make_float4(0.f, 0.f, 0.f, 0.f);
    if (c < 1000) v = *reinterpret_cast<const float4*>(ph + (size_t)c * 128 + c4);
    *reinterpret_cast<float4*>(&ps[row][c4]) = v;
  }
  if (tid < 128) ws_[tid] = fc_w[tid];
  __syncthreads();
  int tx = tid & 15, ty = tid >> 4;   // tx -> c (4 cols), ty -> b (8 rows)
  float acc[8][4] = {};
  for (int h = 0; h < 128; h += 4) {
    float4 w4 = *reinterpret_cast<float4*>(&ws_[h]);
    float4 a4[8], p4[4];
    #pragma unroll
    for (int i = 0; i < 8; ++i) a4[i] = *reinterpret_cast<float4*>(&ih[ty * 8 + i][h]);
    #pragma unroll
    for (int j = 0; j < 4; ++j) p4[j] = *reinterpret_cast<float4*>(&ps[tx * 4 + j][h]);
    #pragma unroll
    for (int i = 0; i < 8; ++i)
      #pragma unroll
      for (int j = 0; j < 4; ++j) {
        acc[i][j] += fmaxf(a4[i].x + p4[j].x, 0.f) * w4.x;
        acc[i][j] += fmaxf(a4[i].y + p4[j].y, 0.f) * w4.y;
        acc[i][j] += fmaxf(a4[i].z + p4[j].z, 0.f) * w4.z;
        acc[i][j] += fmaxf(a4[i].w + p4[j].w, 0.f) * w4.w;
      }
  }
  float fb = fc_b[0];
  #pragma unroll
  for (int i = 0; i < 8; ++i) {
    int b = b0 + ty * 8 + i;
    int c = c0 + tx * 4;
    if (c < 1000) {   // 1000 % 4 == 0 -> all-or-nothing per float4
      float4 v = make_float4(acc[i][0] + fb, acc[i][1] + fb, acc[i][2] + fb, acc[i][3] + fb);
      *reinterpret_cast<float4*>(out + (size_t)b * 1000 + c) = v;
    }
  }
}

extern "C" void kernel_launch(void* const* d_in, const int* in_sizes, int n_in,
                              void* d_out, int out_size, void* d_ws, size_t ws_size,
                              hipStream_t stream) {
  const float* image_feats = (const float*)d_in[0];   // [2048,2048]
  const float* img_proto   = (const float*)d_in[1];   // [1000,2048]
  const float* attributes  = (const float*)d_in[2];   // [1000,312]
  const float* att_g   = (const float*)d_in[4];       // [312,128]
  const float* slim_w  = (const float*)d_in[5];       // [2048,312]
  const float* slim_b  = (const float*)d_in[6];       // [312]
  const float* img_w   = (const float*)d_in[7];       // [2048,128]
  const float* proto_w = (const float*)d_in[8];       // [624,128]
  const float* proto_b = (const float*)d_in[9];       // [1,128]
  const float* fc_w    = (const float*)d_in[10];      // [128,1]
  const float* fc_b    = (const float*)d_in[11];      // [1]
  float* out = (float*)d_out;                         // [2048,1000]

  char* ws = (char*)d_ws;
  size_t o = 0;
  auto alloc = [&](size_t bytes) { size_t r = o; o += (bytes + 255) & ~(size_t)255; return r; };
  ushort_t* imgf_bf = (ushort_t*)(ws + alloc(2048ull * 2048 * 2));  // image_feats bf16
  ushort_t* imgwT   = (ushort_t*)(ws + alloc(128ull * 2048 * 2));   // img_w^T bf16
  ushort_t* imgp_bf = (ushort_t*)(ws + alloc(1008ull * 2048 * 2));  // img_proto bf16, M-pad
  ushort_t* slimT   = (ushort_t*)(ws + alloc(320ull * 2048 * 2));   // slim_w^T bf16, N-pad
  ushort_t* protowT = (ushort_t*)(ws + alloc(128ull * 640 * 2));    // proto_w^T bf16, K-pad
  float* gn        = (float*)(ws + alloc(1000ull * 128 * 4));
  float* proto_red = (float*)(ws + alloc(1000ull * 312 * 4));
  ushort_t* outs_bf = (ushort_t*)(ws + alloc(1008ull * 640 * 2));   // concat outs bf16
  float* img_h     = (float*)(ws + alloc(2048ull * 128 * 4));
  float* ph        = (float*)(ws + alloc(1000ull * 128 * 4));       // proto_h + proto_b

  // straight conversions: imgf (2048 blocks) + imgp (1000 blocks), 2048 elem/block
  cvt2_k<<<3048, 256, 0, stream>>>(image_feats, imgf_bf, 2048, img_proto, imgp_bf);
  // transposes: slimT (2496) + imgwT (1024) + protowT (320)
  cvt_tr3_k<<<3840, 256, 0, stream>>>(slim_w, slimT, img_w, imgwT, proto_w, protowT);

  gn_k<<<125, 128, 0, stream>>>(attributes, att_g, gn);

  // proto_red = img_proto @ slim_w + slim_b   (M=1000,N=312,K=2048)
  mfma_gemm_bt<<<315, 256, 0, stream>>>(imgp_bf, slimT, proto_red, 1000, 312, 2048, 63, 20, slim_b);
  // img_h = image_feats @ img_w               (M=2048,N=128,K=2048)
  mfma_gemm_bt<<<256, 256, 0, stream>>>(imgf_bf, imgwT, img_h, 2048, 128, 2048, 128, 8, nullptr);

  attn_prop_k<<<250, 320, 0, stream>>>(gn, attributes, proto_red, outs_bf);

  // ph = outs @ proto_w + proto_b             (M=1000,N=128,K=640)
  mfma_gemm_bt<<<126, 256, 0, stream>>>(outs_bf, protowT, ph, 1000, 128, 640, 63, 8, proto_b);

  final_k<<<dim3(16, 16), 256, 0, stream>>>(img_h, ph, fc_w, fc_b, out);
}

// Round 3
// 211.314 us; speedup vs baseline: 1.1285x; 1.0737x over previous
//
#include <hip/hip_runtime.h>

typedef unsigned short ushort_t;
typedef __bf16 bf16x8 __attribute__((ext_vector_type(8)));
typedef float f32x4 __attribute__((ext_vector_type(4)));
typedef float f32x2 __attribute__((ext_vector_type(2)));
typedef ushort_t us4 __attribute__((ext_vector_type(4)));

#define T_SOFT 32.0f
#define THRESH 0.76604444311897803f   // cos(40 deg)

__device__ __forceinline__ ushort_t f2bf(float f) {
  union { float f; unsigned u; } x; x.f = f;
  unsigned r = (x.u + 0x7fffu + ((x.u >> 16) & 1u)) >> 16;  // RNE
  return (ushort_t)r;
}

// pack 8 fp32 -> bf16x8, round-half-up via +0x8000 then byte-perm truncate
__device__ __forceinline__ bf16x8 pack8(float4 x, float4 y) {
  union { unsigned u[4]; bf16x8 h; } r;
  union { float4 f; unsigned u[4]; } a, b;
  a.f = x; b.f = y;
  r.u[0] = __builtin_amdgcn_perm(a.u[1] + 0x8000u, a.u[0] + 0x8000u, 0x07060302u);
  r.u[1] = __builtin_amdgcn_perm(a.u[3] + 0x8000u, a.u[2] + 0x8000u, 0x07060302u);
  r.u[2] = __builtin_amdgcn_perm(b.u[1] + 0x8000u, b.u[0] + 0x8000u, 0x07060302u);
  r.u[3] = __builtin_amdgcn_perm(b.u[3] + 0x8000u, b.u[2] + 0x8000u, 0x07060302u);
  return r.h;
}

// ---------------- coalesced LDS-tiled transpose+convert: src[R,C] fp32 -> dst[C,Rpad] bf16 ----------------
// 3 regions in one launch; 32x32 tiles; reads coalesced, writes us4 (8B)
__global__ __launch_bounds__(256) void tr3_k(const float* __restrict__ s0, ushort_t* __restrict__ d0,
                                             const float* __restrict__ s1, ushort_t* __restrict__ d1,
                                             const float* __restrict__ s2, ushort_t* __restrict__ d2) {
  __shared__ float tl[32][33];
  int b = blockIdx.x, tid = threadIdx.x;
  const float* src; ushort_t* dst; int R, C, Rpad, local, ctiles;
  if (b < 640)      { src = s0; dst = d0; R = 2048; C = 312; Rpad = 2048; local = b;       ctiles = 10; }
  else if (b < 896) { src = s1; dst = d1; R = 2048; C = 128; Rpad = 2048; local = b - 640; ctiles = 4;  }
  else              { src = s2; dst = d2; R = 624;  C = 128; Rpad = 640;  local = b - 896; ctiles = 4;  }
  int rt = local / ctiles, ct = local - rt * ctiles;
  int r0 = rt * 32, c0 = ct * 32;
  #pragma unroll
  for (int p = 0; p < 4; ++p) {
    int idx = p * 256 + tid;
    int rr = idx >> 5, cc = idx & 31;
    float v = 0.f;
    if (r0 + rr < R && c0 + cc < C) v = src[(size_t)(r0 + rr) * C + (c0 + cc)];
    tl[cc][rr] = v;
  }
  __syncthreads();
  int cc = tid >> 3, rq = tid & 7;
  if (c0 + cc < C) {
    us4 o;
    o[0] = f2bf(tl[cc][rq * 4 + 0]);
    o[1] = f2bf(tl[cc][rq * 4 + 1]);
    o[2] = f2bf(tl[cc][rq * 4 + 2]);
    o[3] = f2bf(tl[cc][rq * 4 + 3]);
    *reinterpret_cast<us4*>(dst + (size_t)(c0 + cc) * Rpad + r0 + rq * 4) = o;
  }
}

// ---------------- GEMM wave body: C[M,N] = A[M,K](fp32, packed in-reg) @ BT[N,K](bf16)^T ----------------
__device__ __forceinline__ void gemm_f32a(const float* __restrict__ A, const ushort_t* __restrict__ BT,
                                          float* __restrict__ C, int M, int N, int K, int Mt, int Nt,
                                          const float* __restrict__ bias, int wid, int lane) {
  int tm = wid / Nt;
  int tn = wid - tm * Nt;
  if (tm >= Mt) return;
  int l15 = lane & 15;
  int quad = lane >> 4;
  int arow = tm * 16 + l15; if (arow >= M) arow = M - 1;   // clamp: no OOB on unpadded fp32 input
  const float4* ap = reinterpret_cast<const float4*>(A + (size_t)arow * K) + quad * 2;
  const bf16x8* bp = reinterpret_cast<const bf16x8*>(BT + (size_t)(tn * 16 + l15) * K + quad * 8);
  f32x4 acc = {0.f, 0.f, 0.f, 0.f};
  for (int s = 0, steps = K >> 7; s < steps; ++s) {
    float4 a00 = ap[0],  a01 = ap[1];
    float4 a10 = ap[8],  a11 = ap[9];
    float4 a20 = ap[16], a21 = ap[17];
    float4 a30 = ap[24], a31 = ap[25];
    bf16x8 b0 = bp[0], b1 = bp[4], b2 = bp[8], b3 = bp[12];
    ap += 32; bp += 16;
    acc = __builtin_amdgcn_mfma_f32_16x16x32_bf16(pack8(a00, a01), b0, acc, 0, 0, 0);
    acc = __builtin_amdgcn_mfma_f32_16x16x32_bf16(pack8(a10, a11), b1, acc, 0, 0, 0);
    acc = __builtin_amdgcn_mfma_f32_16x16x32_bf16(pack8(a20, a21), b2, acc, 0, 0, 0);
    acc = __builtin_amdgcn_mfma_f32_16x16x32_bf16(pack8(a30, a31), b3, acc, 0, 0, 0);
  }
  int col = tn * 16 + l15;
  if (col >= N) return;
  float bv = bias ? bias[col] : 0.f;
  int row0 = tm * 16 + quad * 4;   // C/D: col=lane&15, row=(lane>>4)*4+reg
  #pragma unroll
  for (int r = 0; r < 4; ++r) {
    int row = row0 + r;
    if (row < M) C[(size_t)row * N + col] = acc[r] + bv;
  }
}

// ---------------- mega: gn (125 blocks) + gemm proto_red (315) + gemm img_h (256) ----------------
__global__ __launch_bounds__(256) void mega_k(
    const float* __restrict__ attributes, const float* __restrict__ att_g, float* __restrict__ gn,
    const float* __restrict__ img_proto, const ushort_t* __restrict__ slimT,
    float* __restrict__ proto_red, const float* __restrict__ slim_b,
    const float* __restrict__ image_feats, const ushort_t* __restrict__ imgwT,
    float* __restrict__ img_h) {
  int b = blockIdx.x, tid = threadIdx.x;
  if (b < 125) {
    // gn = normalize(attributes @ att_g); 256 threads, upper 2 waves duplicate lower (benign)
    __shared__ float a_lds[8][316];
    __shared__ float red2[8][2];
    int h = tid & 127;
    int c0 = b * 8;
    for (int idx = tid; idx < 8 * 312; idx += 256) {
      int r = idx / 312;
      int k = idx - r * 312;
      a_lds[r][k] = attributes[(c0 + r) * 312 + k];
    }
    __syncthreads();
    float acc[8] = {0.f,0.f,0.f,0.f,0.f,0.f,0.f,0.f};
    for (int k = 0; k < 312; k += 4) {
      float w0 = att_g[(k + 0) * 128 + h];
      float w1 = att_g[(k + 1) * 128 + h];
      float w2 = att_g[(k + 2) * 128 + h];
      float w3 = att_g[(k + 3) * 128 + h];
      #pragma unroll
      for (int r = 0; r < 8; ++r) {
        float4 a4 = *reinterpret_cast<const float4*>(&a_lds[r][k]);
        acc[r] += a4.x * w0 + a4.y * w1 + a4.z * w2 + a4.w * w3;
      }
    }
    int lane = tid & 63, wvid = (tid >> 6) & 1;
    #pragma unroll
    for (int r = 0; r < 8; ++r) {
      float v = acc[r] * acc[r];
      #pragma unroll
      for (int off = 32; off > 0; off >>= 1) v += __shfl_xor(v, off, 64);
      if (lane == 0) red2[r][wvid] = v;   // waves 0/2 and 1/3 write identical values
    }
    __syncthreads();
    #pragma unroll
    for (int r = 0; r < 8; ++r) {
      float nrm = fmaxf(sqrtf(red2[r][0] + red2[r][1]), 1e-12f);
      gn[(c0 + r) * 128 + h] = acc[r] / nrm;
    }
    return;
  }
  int lane = tid & 63;
  if (b < 440) {
    int wid = (b - 125) * 4 + (tid >> 6);
    gemm_f32a(img_proto, slimT, proto_red, 1000, 312, 2048, 63, 20, slim_b, wid, lane);
  } else {
    int wid = (b - 440) * 4 + (tid >> 6);
    gemm_f32a(image_feats, imgwT, img_h, 2048, 128, 2048, 128, 8, nullptr, wid, lane);
  }
}

// ---------------- bf16-A MFMA GEMM (for ph = outs @ proto_w + proto_b) ----------------
__global__ __launch_bounds__(256) void mfma_gemm_bt(
    const ushort_t* __restrict__ A, const ushort_t* __restrict__ BT,
    float* __restrict__ C, int M, int N, int K, int Mt, int Nt,
    const float* __restrict__ bias) {
  int wid = blockIdx.x * 4 + (threadIdx.x >> 6);
  int lane = threadIdx.x & 63;
  int tm = wid / Nt;
  int tn = wid - tm * Nt;
  if (tm >= Mt) return;
  int l15 = lane & 15;
  int quad = lane >> 4;
  const bf16x8* ap = reinterpret_cast<const bf16x8*>(A + (size_t)(tm * 16 + l15) * K + quad * 8);
  const bf16x8* bp = reinterpret_cast<const bf16x8*>(BT + (size_t)(tn * 16 + l15) * K + quad * 8);
  f32x4 acc = {0.f, 0.f, 0.f, 0.f};
  for (int s = 0, steps = K >> 7; s < steps; ++s) {
    bf16x8 a0 = ap[0],  b0 = bp[0];
    bf16x8 a1 = ap[4],  b1 = bp[4];
    bf16x8 a2 = ap[8],  b2 = bp[8];
    bf16x8 a3 = ap[12], b3 = bp[12];
    ap += 16; bp += 16;
    acc = __builtin_amdgcn_mfma_f32_16x16x32_bf16(a0, b0, acc, 0, 0, 0);
    acc = __builtin_amdgcn_mfma_f32_16x16x32_bf16(a1, b1, acc, 0, 0, 0);
    acc = __builtin_amdgcn_mfma_f32_16x16x32_bf16(a2, b2, acc, 0, 0, 0);
    acc = __builtin_amdgcn_mfma_f32_16x16x32_bf16(a3, b3, acc, 0, 0, 0);
  }
  int col = tn * 16 + l15;
  if (col >= N) return;
  float bv = bias ? bias[col] : 0.f;
  int row0 = tm * 16 + quad * 4;
  #pragma unroll
  for (int r = 0; r < 4; ++r) {
    int row = row0 + r;
    if (row < M) C[(size_t)row * N + col] = acc[r] + bv;
  }
}

// ---------------- fused sim -> mask -> softmax -> propagate ----------------
__global__ __launch_bounds__(320) void attn_prop_k(
    const float* __restrict__ gn, const float* __restrict__ attributes,
    const float* __restrict__ proto_red, ushort_t* __restrict__ outs) {
  __shared__ float gni[4][128];
  __shared__ float wv[4][1000];
  __shared__ float wred[4];
  __shared__ int njs;
  __shared__ int jlist[1000];
  int tid = threadIdx.x;
  int i0 = blockIdx.x * 4;
  if (tid < 4) wred[tid] = 0.f;
  if (tid == 0) njs = 0;
  for (int idx = tid; idx < 512; idx += 320) gni[idx >> 7][idx & 127] = gn[i0 * 128 + idx];
  __syncthreads();
  float lsum[4] = {0.f,0.f,0.f,0.f};
  for (int j = tid; j < 1000; j += 320) {
    const float4* gj = reinterpret_cast<const float4*>(gn + (size_t)j * 128);
    float d[4] = {0.f,0.f,0.f,0.f};
    #pragma unroll 4
    for (int k4 = 0; k4 < 32; ++k4) {
      float4 v = gj[k4];
      int k = k4 * 4;
      #pragma unroll
      for (int r = 0; r < 4; ++r)
        d[r] += v.x * gni[r][k] + v.y * gni[r][k+1] + v.z * gni[r][k+2] + v.w * gni[r][k+3];
    }
    int any = 0;
    #pragma unroll
    for (int r = 0; r < 4; ++r) {
      float w = (d[r] > THRESH) ? __expf(T_SOFT * d[r]) : 0.f;  // max-shift cancels in normalize
      wv[r][j] = w;
      lsum[r] += w;
      any |= (w > 0.f) ? 1 : 0;
    }
    if (any) { int p = atomicAdd(&njs, 1); jlist[p] = j; }
  }
  #pragma unroll
  for (int r = 0; r < 4; ++r) {
    float v = lsum[r];
    #pragma unroll
    for (int off = 32; off > 0; off >>= 1) v += __shfl_down(v, off, 64);
    if ((tid & 63) == 0) atomicAdd(&wred[r], v);
  }
  __syncthreads();
  if (tid < 312) {
    int nj = njs;
    float aa[4] = {0.f,0.f,0.f,0.f}, pp[4] = {0.f,0.f,0.f,0.f};
    for (int t = 0; t < nj; ++t) {
      int j = jlist[t];
      float av = attributes[(size_t)j * 312 + tid];
      float pv = proto_red[(size_t)j * 312 + tid];
      #pragma unroll
      for (int r = 0; r < 4; ++r) {
        float w = wv[r][j];
        aa[r] += w * av;
        pp[r] += w * pv;
      }
    }
    #pragma unroll
    for (int r = 0; r < 4; ++r) {
      float inv = 1.f / wred[r];
      size_t rowoff = (size_t)(i0 + r) * 640;
      outs[rowoff + tid]       = f2bf(aa[r] * inv);
      outs[rowoff + 312 + tid] = f2bf(pp[r] * inv);
    }
  }
  if (tid < 16) {
    #pragma unroll
    for (int r = 0; r < 4; ++r) outs[(size_t)(i0 + r) * 640 + 624 + tid] = 0;
  }
}

// ---------------- final: out[b,c] = fc_b + sum_h relu(img_h[b,h]+ph[c,h]) * fc_w[h] ----------------
// 128x64 tile, 8x4 per thread, packed-fp32 (f32x2 -> v_pk_*) inner loop
__global__ __launch_bounds__(256) void final_k(
    const float* __restrict__ img_h, const float* __restrict__ ph,
    const float* __restrict__ fc_w, const float* __restrict__ fc_b,
    float* __restrict__ out) {
  __shared__ float ih[128][132];
  __shared__ float ps[64][132];
  __shared__ float ws_[128];
  int tid = threadIdx.x;
  int b0 = blockIdx.x * 128;
  int c0 = blockIdx.y * 64;
  for (int idx = tid; idx < 4096; idx += 256) {
    int row = idx >> 5, c4 = (idx & 31) * 4;
    float4 v = *reinterpret_cast<const float4*>(img_h + (size_t)(b0 + row) * 128 + c4);
    *reinterpret_cast<float4*>(&ih[row][c4]) = v;
  }
  for (int idx = tid; idx < 2048; idx += 256) {
    int row = idx >> 5, c4 = (idx & 31) * 4;
    int c = c0 + row;
    float4 v = make_float4(0.f, 0.f, 0.f, 0.f);
    if (c < 1000) v = *reinterpret_cast<const float4*>(ph + (size_t)c * 128 + c4);
    *reinterpret_cast<float4*>(&ps[row][c4]) = v;
  }
  if (tid < 128) ws_[tid] = fc_w[tid];
  __syncthreads();
  int tx = tid & 15, ty = tid >> 4;
  f32x2 acc[8][4] = {};
  const f32x2 zero2 = {0.f, 0.f};
  for (int h = 0; h < 128; h += 4) {
    float4 w4 = *reinterpret_cast<float4*>(&ws_[h]);
    f32x2 wlo = {w4.x, w4.y}, whi = {w4.z, w4.w};
    float4 a4[8], p4[4];
    #pragma unroll
    for (int i = 0; i < 8; ++i) a4[i] = *reinterpret_cast<float4*>(&ih[ty * 8 + i][h]);
    #pragma unroll
    for (int j = 0; j < 4; ++j) p4[j] = *reinterpret_cast<float4*>(&ps[tx * 4 + j][h]);
    #pragma unroll
    for (int i = 0; i < 8; ++i) {
      f32x2 alo = {a4[i].x, a4[i].y}, ahi = {a4[i].z, a4[i].w};
      #pragma unroll
      for (int j = 0; j < 4; ++j) {
        f32x2 plo = {p4[j].x, p4[j].y}, phi = {p4[j].z, p4[j].w};
        f32x2 t0 = __builtin_elementwise_max(alo + plo, zero2);
        f32x2 t1 = __builtin_elementwise_max(ahi + phi, zero2);
        acc[i][j] = acc[i][j] + t0 * wlo;   // ffp-contract -> v_pk_fma_f32
        acc[i][j] = acc[i][j] + t1 * whi;
      }
    }
  }
  float fb = fc_b[0];
  #pragma unroll
  for (int i = 0; i < 8; ++i) {
    int b = b0 + ty * 8 + i;
    int c = c0 + tx * 4;
    if (c < 1000) {
      float4 v = make_float4(acc[i][0].x + acc[i][0].y + fb, acc[i][1].x + acc[i][1].y + fb,
                             acc[i][2].x + acc[i][2].y + fb, acc[i][3].x + acc[i][3].y + fb);
      *reinterpret_cast<float4*>(out + (size_t)b * 1000 + c) = v;
    }
  }
}

extern "C" void kernel_launch(void* const* d_in, const int* in_sizes, int n_in,
                              void* d_out, int out_size, void* d_ws, size_t ws_size,
                              hipStream_t stream) {
  const float* image_feats = (const float*)d_in[0];   // [2048,2048]
  const float* img_proto   = (const float*)d_in[1];   // [1000,2048]
  const float* attributes  = (const float*)d_in[2];   // [1000,312]
  const float* att_g   = (const float*)d_in[4];       // [312,128]
  const float* slim_w  = (const float*)d_in[5];       // [2048,312]
  const float* slim_b  = (const float*)d_in[6];       // [312]
  const float* img_w   = (const float*)d_in[7];       // [2048,128]
  const float* proto_w = (const float*)d_in[8];       // [624,128]
  const float* proto_b = (const float*)d_in[9];       // [1,128]
  const float* fc_w    = (const float*)d_in[10];      // [128,1]
  const float* fc_b    = (const float*)d_in[11];      // [1]
  float* out = (float*)d_out;                         // [2048,1000]

  char* ws = (char*)d_ws;
  size_t o = 0;
  auto alloc = [&](size_t bytes) { size_t r = o; o += (bytes + 255) & ~(size_t)255; return r; };
  ushort_t* imgwT   = (ushort_t*)(ws + alloc(128ull * 2048 * 2));   // img_w^T bf16
  ushort_t* slimT   = (ushort_t*)(ws + alloc(320ull * 2048 * 2));   // slim_w^T bf16, N-pad (rows 312-319 junk, discarded)
  ushort_t* protowT = (ushort_t*)(ws + alloc(128ull * 640 * 2));    // proto_w^T bf16, K-pad zeros
  float* gn        = (float*)(ws + alloc(1000ull * 128 * 4));
  float* proto_red = (float*)(ws + alloc(1000ull * 312 * 4));
  ushort_t* outs_bf = (ushort_t*)(ws + alloc(1008ull * 640 * 2));   // concat outs bf16, M/K-pad
  float* img_h     = (float*)(ws + alloc(2048ull * 128 * 4));
  float* ph        = (float*)(ws + alloc(1000ull * 128 * 4));

  // transposes: slimT (640 blocks) + imgwT (256) + protowT (80)
  tr3_k<<<976, 256, 0, stream>>>(slim_w, slimT, img_w, imgwT, proto_w, protowT);

  // gn + proto_red GEMM + img_h GEMM in one launch (fp32 A packed in-register)
  mega_k<<<696, 256, 0, stream>>>(attributes, att_g, gn,
                                  img_proto, slimT, proto_red, slim_b,
                                  image_feats, imgwT, img_h);

  attn_prop_k<<<250, 320, 0, stream>>>(gn, attributes, proto_red, outs_bf);

  // ph = outs @ proto_w + proto_b   (M=1000,N=128,K=640)
  mfma_gemm_bt<<<126, 256, 0, stream>>>(outs_bf, protowT, ph, 1000, 128, 640, 63, 8, proto_b);

  final_k<<<dim3(16, 16), 256, 0, stream>>>(img_h, ph, fc_w, fc_b, out);
}